// Round 12
// baseline (940.803 us; speedup 1.0000x reference)
//
#include <hip/hip_runtime.h>

#define NN 100000
#define D 64
#define G 64
#define BN_EPS 1e-5f

typedef unsigned short ushort_t;
typedef unsigned int uint_t;

__device__ __forceinline__ ushort_t f2b_rne(float f) {
    uint_t u = __float_as_uint(f);
    uint_t r = (u + 0x7FFFu + ((u >> 16) & 1u)) >> 16;
    return (ushort_t)r;
}
__device__ __forceinline__ float b2f_lo(uint_t u) { return __uint_as_float(u << 16); }
__device__ __forceinline__ float b2f_hi(uint_t u) { return __uint_as_float(u & 0xFFFF0000u); }

// ================= CSR build =================

__global__ void k_zero(int* cnt, float* sums16, int n) {
    int i = blockIdx.x * blockDim.x + threadIdx.x;
    if (i < n) cnt[i] = 0;
    if (i < 2176) sums16[i] = 0.0f;  // 16*128 slots + 128 final
}

__global__ void k_count8(const int* __restrict__ src, const int* __restrict__ dst,
                         int* cnt, int E) {
    int t = blockIdx.x * blockDim.x + threadIdx.x;
    int e0 = t * 8;
    if (e0 >= E) return;
    if (e0 + 8 <= E) {
        int4 sa = *(const int4*)(src + e0);
        int4 sb = *(const int4*)(src + e0 + 4);
        int4 da = *(const int4*)(dst + e0);
        int4 db = *(const int4*)(dst + e0 + 4);
        if (sa.x != da.x) atomicAdd(&cnt[da.x], 1);
        if (sa.y != da.y) atomicAdd(&cnt[da.y], 1);
        if (sa.z != da.z) atomicAdd(&cnt[da.z], 1);
        if (sa.w != da.w) atomicAdd(&cnt[da.w], 1);
        if (sb.x != db.x) atomicAdd(&cnt[db.x], 1);
        if (sb.y != db.y) atomicAdd(&cnt[db.y], 1);
        if (sb.z != db.z) atomicAdd(&cnt[db.z], 1);
        if (sb.w != db.w) atomicAdd(&cnt[db.w], 1);
    } else {
        for (int e = e0; e < E; ++e) {
            int s = src[e], d = dst[e];
            if (s != d) atomicAdd(&cnt[d], 1);
        }
    }
}

// fused: dinv[i] = rsqrt(cnt+1); xb[i][c] = bf16(x[i][c] * dinv[i])
__global__ void k_dinv_xb(const int* __restrict__ cnt, const float* __restrict__ x,
                          float* __restrict__ dinv, ushort_t* __restrict__ xb, int n) {
    int i = blockIdx.x * blockDim.x + threadIdx.x;  // 4 channels per thread
    int total = n * (D / 4);
    if (i >= total) return;
    int row = i >> 4;
    float di = rsqrtf((float)cnt[row] + 1.0f);
    if ((i & 15) == 0) dinv[row] = di;
    float4 v = ((const float4*)x)[i];
    ushort4 o;
    o.x = f2b_rne(v.x * di);
    o.y = f2b_rne(v.y * di);
    o.z = f2b_rne(v.z * di);
    o.w = f2b_rne(v.w * di);
    ((ushort4*)xb)[i] = o;
}

// exclusive scan of cnt -> row_ptr (3 phases)
__global__ __launch_bounds__(1024) void k_scanA(const int* __restrict__ cnt,
                                                int* __restrict__ row_ptr,
                                                int* __restrict__ bsum, int n) {
    __shared__ int sm[1024];
    int tid = threadIdx.x;
    int i = blockIdx.x * 1024 + tid;
    int v = (i < n) ? cnt[i] : 0;
    int xv = v;
    sm[tid] = xv;
    __syncthreads();
    for (int off = 1; off < 1024; off <<= 1) {
        int t = (tid >= off) ? sm[tid - off] : 0;
        __syncthreads();
        xv += t;
        sm[tid] = xv;
        __syncthreads();
    }
    if (i < n) row_ptr[i] = xv - v;
    if (tid == 1023) bsum[blockIdx.x] = xv;
}

__global__ void k_scanB(int* bsum, int nb) {
    __shared__ int sm[128];
    int tid = threadIdx.x;
    int v = (tid < nb) ? bsum[tid] : 0;
    int xv = v;
    sm[tid] = xv;
    __syncthreads();
    for (int off = 1; off < 128; off <<= 1) {
        int t = (tid >= off) ? sm[tid - off] : 0;
        __syncthreads();
        xv += t;
        sm[tid] = xv;
        __syncthreads();
    }
    if (tid < nb) bsum[tid] = xv - v;
}

__global__ void k_scanC(int* __restrict__ row_ptr, int* __restrict__ cursor,
                        const int* __restrict__ bsum, const int* __restrict__ cnt,
                        int n) {
    int i = blockIdx.x * blockDim.x + threadIdx.x;
    if (i < n) {
        int r = row_ptr[i] + bsum[i >> 10];
        row_ptr[i] = r;
        cursor[i] = r;
        if (i == n - 1) row_ptr[n] = r + cnt[i];  // sentinel: total kept edges
    }
}

// place packed edge payload: src | (dst_local << 17)   (src < 2^17, dl < 64)
__global__ void k_place8(const int* __restrict__ src, const int* __restrict__ dst,
                         int* cursor, uint_t* __restrict__ packed, int E) {
    int t = blockIdx.x * blockDim.x + threadIdx.x;
    int e0 = t * 8;
    if (e0 >= E) return;
    if (e0 + 8 <= E) {
        int4 sa = *(const int4*)(src + e0);
        int4 sb = *(const int4*)(src + e0 + 4);
        int4 da = *(const int4*)(dst + e0);
        int4 db = *(const int4*)(dst + e0 + 4);
        if (sa.x != da.x) packed[atomicAdd(&cursor[da.x], 1)] = (uint_t)sa.x | ((uint_t)(da.x & 63) << 17);
        if (sa.y != da.y) packed[atomicAdd(&cursor[da.y], 1)] = (uint_t)sa.y | ((uint_t)(da.y & 63) << 17);
        if (sa.z != da.z) packed[atomicAdd(&cursor[da.z], 1)] = (uint_t)sa.z | ((uint_t)(da.z & 63) << 17);
        if (sa.w != da.w) packed[atomicAdd(&cursor[da.w], 1)] = (uint_t)sa.w | ((uint_t)(da.w & 63) << 17);
        if (sb.x != db.x) packed[atomicAdd(&cursor[db.x], 1)] = (uint_t)sb.x | ((uint_t)(db.x & 63) << 17);
        if (sb.y != db.y) packed[atomicAdd(&cursor[db.y], 1)] = (uint_t)sb.y | ((uint_t)(db.y & 63) << 17);
        if (sb.z != db.z) packed[atomicAdd(&cursor[db.z], 1)] = (uint_t)sb.z | ((uint_t)(db.z & 63) << 17);
        if (sb.w != db.w) packed[atomicAdd(&cursor[db.w], 1)] = (uint_t)sb.w | ((uint_t)(db.w & 63) << 17);
    } else {
        for (int e = e0; e < E; ++e) {
            int s = src[e], d = dst[e];
            if (s != d) packed[atomicAdd(&cursor[d], 1)] = (uint_t)s | ((uint_t)(d & 63) << 17);
        }
    }
}

// ================= edge-parallel LDS aggregation + GEMM + BN stats =================
// Block owns G=64 consecutive dst nodes and their contiguous packed-edge segment.
// Edge phase: each 32-lane half-wave streams edges (4-deep), ds_add_f32 into Lacc.
// Finish: agg = did*(did*x + Lacc); shfl-GEMM; per-block stats -> 16-slot flush.
__global__ __launch_bounds__(256) void k_edge_gemm(
        const int* __restrict__ row_ptr, const uint_t* __restrict__ packed,
        const float* __restrict__ x, const ushort_t* __restrict__ xb,
        const float* __restrict__ dinv, const float* __restrict__ W,
        float* __restrict__ out, float* sums16, int n) {
    __shared__ float Ws[64 * 64];
    __shared__ float Lacc[G * 64];
    int tid = threadIdx.x;
    for (int i = tid; i < 64 * 64; i += 256) Ws[i] = W[i];
    for (int i = tid; i < G * 64; i += 256) Lacc[i] = 0.0f;
    __syncthreads();

    int r0 = blockIdx.x * G;
    int rend = r0 + G < n ? r0 + G : n;
    int estart = row_ptr[r0];
    int eend = row_ptr[rend];

    int hw = tid >> 5;   // 0..7 half-wave
    int sl = tid & 31;
    int c0 = sl * 2;

    for (int eb = estart + hw * 4; eb < eend; eb += 32) {
        int m = eend - eb;
        if (m > 4) m = 4;
        uint_t v[4], rv[4];
#pragma unroll
        for (int u = 0; u < 4; ++u) v[u] = packed[eb + (u < m ? u : 0)];
#pragma unroll
        for (int u = 0; u < 4; ++u) {
            int s = v[u] & 0x1FFFF;
            rv[u] = *(const uint_t*)&xb[(size_t)s * D + c0];
        }
#pragma unroll
        for (int u = 0; u < 4; ++u) {
            if (u < m) {
                int dl = (v[u] >> 17) & 63;
                atomicAdd(&Lacc[dl * 64 + c0], b2f_lo(rv[u]));
                atomicAdd(&Lacc[dl * 64 + c0 + 1], b2f_hi(rv[u]));
            }
        }
    }
    __syncthreads();

    // GEMM + stats: 4 waves x 16 rows
    int wave = tid >> 6, lane = tid & 63;
    float ssum = 0.0f, sqsum = 0.0f;
    for (int rr = 0; rr < 16; ++rr) {
        int r = wave * 16 + rr;
        int d = r0 + r;
        if (d >= n) break;
        float did = dinv[d];
        float self = x[(size_t)d * D + lane];
        float agg = did * (did * self + Lacc[r * 64 + lane]);
        float o = 0.0f;
#pragma unroll
        for (int k = 0; k < 64; ++k) {
            o += __shfl(agg, k) * Ws[k * 64 + lane];
        }
        out[(size_t)d * D + lane] = o;
        ssum += o;
        sqsum += o * o;
    }
    __syncthreads();  // all Lacc reads done; reuse as reduction scratch
    Lacc[wave * 64 + lane] = ssum;
    Lacc[256 + wave * 64 + lane] = sqsum;
    __syncthreads();
    if (tid < 64) {
        float ts = Lacc[tid] + Lacc[64 + tid] + Lacc[128 + tid] + Lacc[192 + tid];
        float tq = Lacc[256 + tid] + Lacc[320 + tid] + Lacc[384 + tid] + Lacc[448 + tid];
        float* slot = sums16 + (size_t)(blockIdx.x & 15) * 128;
        atomicAdd(&slot[tid], ts);
        atomicAdd(&slot[64 + tid], tq);
    }
}

// fold 16 slots -> final sums (stored at sums16 + 2048)
__global__ void k_finalize(float* sums16) {
    int i = threadIdx.x;  // 128 threads
    float s = 0.0f;
#pragma unroll
    for (int j = 0; j < 16; ++j) s += sums16[j * 128 + i];
    sums16[2048 + i] = s;
}

// ================= BN apply + ReLU (float4, in place) =================
// GCN bias b cancels exactly in BatchNorm: omitted.
__global__ void k_bn_apply(float* out, const float* __restrict__ sums,
                           const float* __restrict__ bnw, const float* __restrict__ bnb,
                           int n) {
    int i = blockIdx.x * blockDim.x + threadIdx.x;
    int total = n * (D / 4);
    if (i >= total) return;
    int c0 = (i * 4) & 63;
    const float invn = 1.0f / (float)NN;
    float4 v = ((const float4*)out)[i];
    float r[4] = {v.x, v.y, v.z, v.w};
#pragma unroll
    for (int j = 0; j < 4; ++j) {
        int c = c0 + j;
        float mean = sums[c] * invn;
        float var = sums[64 + c] * invn - mean * mean;
        if (var < 0.0f) var = 0.0f;
        float scale = bnw[c] * rsqrtf(var + BN_EPS);
        float y = (r[j] - mean) * scale + bnb[c];
        r[j] = y > 0.0f ? y : 0.0f;
    }
    float4 o = {r[0], r[1], r[2], r[3]};
    ((float4*)out)[i] = o;
}

extern "C" void kernel_launch(void* const* d_in, const int* in_sizes, int n_in,
                              void* d_out, int out_size, void* d_ws, size_t ws_size,
                              hipStream_t stream) {
    const float* x = (const float*)d_in[0];
    const int* ei = (const int*)d_in[1];
    const float* W = (const float*)d_in[3];
    const float* bnw = (const float*)d_in[5];
    const float* bnb = (const float*)d_in[6];
    float* out = (float*)d_out;

    const int n = in_sizes[0] / D;   // 100000
    const int E = in_sizes[1] / 2;   // 1600000
    const int* src = ei;
    const int* dst = ei + E;

    int* cnt = (int*)d_ws;
    int* row_ptr = cnt + n;                  // n+1 (sentinel)
    int* cursor = row_ptr + n + 1;
    float* dinv = (float*)(cursor + n);
    uint_t* packed = (uint_t*)(dinv + n);    // E
    int* bsum = (int*)(packed + E);          // 128 ints
    float* sums16 = (float*)(bsum + 128);    // 16*128 slots + 128 final
    float* sums = sums16 + 2048;
    size_t off = ((size_t)((char*)(sums16 + 2176) - (char*)d_ws) + 15) & ~(size_t)15;
    ushort_t* xb = (ushort_t*)((char*)d_ws + off);

    const int nb = (n + 1023) / 1024;  // 98

    k_zero<<<(n + 255) / 256, 256, 0, stream>>>(cnt, sums16, n);
    k_count8<<<((E + 7) / 8 + 255) / 256, 256, 0, stream>>>(src, dst, cnt, E);
    k_dinv_xb<<<(n * (D / 4) + 255) / 256, 256, 0, stream>>>(cnt, x, dinv, xb, n);
    k_scanA<<<nb, 1024, 0, stream>>>(cnt, row_ptr, bsum, n);
    k_scanB<<<1, 128, 0, stream>>>(bsum, nb);
    k_scanC<<<(n + 255) / 256, 256, 0, stream>>>(row_ptr, cursor, bsum, cnt, n);
    k_place8<<<((E + 7) / 8 + 255) / 256, 256, 0, stream>>>(src, dst, cursor, packed, E);

    const int nseg = (n + G - 1) / G;  // 1563
    k_edge_gemm<<<nseg, 256, 0, stream>>>(row_ptr, packed, x, xb, dinv, W,
                                          out, sums16, n);
    k_finalize<<<1, 128, 0, stream>>>(sums16);
    k_bn_apply<<<(n * (D / 4) + 255) / 256, 256, 0, stream>>>(out, sums, bnw, bnb, n);
}

// Round 13
// 411.266 us; speedup vs baseline: 2.2876x; 2.2876x over previous
//
#include <hip/hip_runtime.h>

#define NN 100000
#define D 64
#define BN_EPS 1e-5f

typedef unsigned short ushort_t;
typedef unsigned int uint_t;

__device__ __forceinline__ ushort_t f2b_rne(float f) {
    uint_t u = __float_as_uint(f);
    uint_t r = (u + 0x7FFFu + ((u >> 16) & 1u)) >> 16;
    return (ushort_t)r;
}
__device__ __forceinline__ float b2f_lo(uint_t u) { return __uint_as_float(u << 16); }
__device__ __forceinline__ float b2f_hi(uint_t u) { return __uint_as_float(u & 0xFFFF0000u); }

// ================= CSR build =================

__global__ void k_zero(int* cnt, float* sums16, int n) {
    int i = blockIdx.x * blockDim.x + threadIdx.x;
    if (i < n) cnt[i] = 0;
    if (i < 2176) sums16[i] = 0.0f;  // 16*128 slots + 128 final
}

__global__ void k_count8(const int* __restrict__ src, const int* __restrict__ dst,
                         int* cnt, int E) {
    int t = blockIdx.x * blockDim.x + threadIdx.x;
    int e0 = t * 8;
    if (e0 >= E) return;
    if (e0 + 8 <= E) {
        int4 sa = *(const int4*)(src + e0);
        int4 sb = *(const int4*)(src + e0 + 4);
        int4 da = *(const int4*)(dst + e0);
        int4 db = *(const int4*)(dst + e0 + 4);
        if (sa.x != da.x) atomicAdd(&cnt[da.x], 1);
        if (sa.y != da.y) atomicAdd(&cnt[da.y], 1);
        if (sa.z != da.z) atomicAdd(&cnt[da.z], 1);
        if (sa.w != da.w) atomicAdd(&cnt[da.w], 1);
        if (sb.x != db.x) atomicAdd(&cnt[db.x], 1);
        if (sb.y != db.y) atomicAdd(&cnt[db.y], 1);
        if (sb.z != db.z) atomicAdd(&cnt[db.z], 1);
        if (sb.w != db.w) atomicAdd(&cnt[db.w], 1);
    } else {
        for (int e = e0; e < E; ++e) {
            int s = src[e], d = dst[e];
            if (s != d) atomicAdd(&cnt[d], 1);
        }
    }
}

// fused: dinv[i] = rsqrt(cnt+1); xb[i][c] = bf16(x[i][c] * dinv[i])
__global__ void k_dinv_xb(const int* __restrict__ cnt, const float* __restrict__ x,
                          float* __restrict__ dinv, ushort_t* __restrict__ xb, int n) {
    int i = blockIdx.x * blockDim.x + threadIdx.x;  // 4 channels per thread
    int total = n * (D / 4);
    if (i >= total) return;
    int row = i >> 4;
    float di = rsqrtf((float)cnt[row] + 1.0f);
    if ((i & 15) == 0) dinv[row] = di;
    float4 v = ((const float4*)x)[i];
    ushort4 o;
    o.x = f2b_rne(v.x * di);
    o.y = f2b_rne(v.y * di);
    o.z = f2b_rne(v.z * di);
    o.w = f2b_rne(v.w * di);
    ((ushort4*)xb)[i] = o;
}

// exclusive scan of cnt -> row_ptr (3 phases)
__global__ __launch_bounds__(1024) void k_scanA(const int* __restrict__ cnt,
                                                int* __restrict__ row_ptr,
                                                int* __restrict__ bsum, int n) {
    __shared__ int sm[1024];
    int tid = threadIdx.x;
    int i = blockIdx.x * 1024 + tid;
    int v = (i < n) ? cnt[i] : 0;
    int xv = v;
    sm[tid] = xv;
    __syncthreads();
    for (int off = 1; off < 1024; off <<= 1) {
        int t = (tid >= off) ? sm[tid - off] : 0;
        __syncthreads();
        xv += t;
        sm[tid] = xv;
        __syncthreads();
    }
    if (i < n) row_ptr[i] = xv - v;
    if (tid == 1023) bsum[blockIdx.x] = xv;
}

__global__ void k_scanB(int* bsum, int nb) {
    __shared__ int sm[128];
    int tid = threadIdx.x;
    int v = (tid < nb) ? bsum[tid] : 0;
    int xv = v;
    sm[tid] = xv;
    __syncthreads();
    for (int off = 1; off < 128; off <<= 1) {
        int t = (tid >= off) ? sm[tid - off] : 0;
        __syncthreads();
        xv += t;
        sm[tid] = xv;
        __syncthreads();
    }
    if (tid < nb) bsum[tid] = xv - v;
}

__global__ void k_scanC(int* __restrict__ row_ptr, int* __restrict__ cursor,
                        const int* __restrict__ bsum, int n) {
    int i = blockIdx.x * blockDim.x + threadIdx.x;
    if (i < n) {
        int r = row_ptr[i] + bsum[i >> 10];
        row_ptr[i] = r;
        cursor[i] = r;
    }
}

__global__ void k_place8(const int* __restrict__ src, const int* __restrict__ dst,
                         int* cursor, int* __restrict__ srcid, int E) {
    int t = blockIdx.x * blockDim.x + threadIdx.x;
    int e0 = t * 8;
    if (e0 >= E) return;
    if (e0 + 8 <= E) {
        int4 sa = *(const int4*)(src + e0);
        int4 sb = *(const int4*)(src + e0 + 4);
        int4 da = *(const int4*)(dst + e0);
        int4 db = *(const int4*)(dst + e0 + 4);
        if (sa.x != da.x) srcid[atomicAdd(&cursor[da.x], 1)] = sa.x;
        if (sa.y != da.y) srcid[atomicAdd(&cursor[da.y], 1)] = sa.y;
        if (sa.z != da.z) srcid[atomicAdd(&cursor[da.z], 1)] = sa.z;
        if (sa.w != da.w) srcid[atomicAdd(&cursor[da.w], 1)] = sa.w;
        if (sb.x != db.x) srcid[atomicAdd(&cursor[db.x], 1)] = sb.x;
        if (sb.y != db.y) srcid[atomicAdd(&cursor[db.y], 1)] = sb.y;
        if (sb.z != db.z) srcid[atomicAdd(&cursor[db.z], 1)] = sb.z;
        if (sb.w != db.w) srcid[atomicAdd(&cursor[db.w], 1)] = sb.w;
    } else {
        for (int e = e0; e < E; ++e) {
            int s = src[e], d = dst[e];
            if (s != d) srcid[atomicAdd(&cursor[d], 1)] = s;
        }
    }
}

// ================= fused gather(bf16) + LDS-staged GEMM + BN stats =================
// Gather phase: 2 nodes per wave (32-lane halves), lane owns 2 channels via uint,
// 8-deep unroll, self term read from xb too (agg = did * sum of xb rows incl self).
// agg staged to Lagg; GEMM phase: one wave per row, single-float 64-shfl loop
// (register-lean; goal VGPR <= 64 for 8 waves/SIMD).
__global__ __launch_bounds__(256) void k_gather2(
        const int* __restrict__ row_ptr, const int* __restrict__ cnt,
        const int* __restrict__ srcid, const ushort_t* __restrict__ xb,
        const float* __restrict__ dinv, const float* __restrict__ W,
        float* __restrict__ out, float* sums16, int n) {
    __shared__ float Ws[64 * 64];
    __shared__ float Lagg[8 * 64];
    __shared__ float ls[4][64], lq[4][64];
    int tid = threadIdx.x;
    for (int i = tid; i < 64 * 64; i += 256) Ws[i] = W[i];

    int wave = tid >> 6, lane = tid & 63;
    int sl = lane & 31;
    int half = lane >> 5;
    int c0 = sl * 2;
    int nl = wave * 2 + half;           // node-local 0..7
    int d = blockIdx.x * 8 + nl;
    bool valid = d < n;

    int base = 0, c = 0;
    float did = 0.0f;
    float2 acc = {0.0f, 0.0f};
    if (valid) {
        base = row_ptr[d];
        c = cnt[d];
        did = dinv[d];
        uint_t rs = *(const uint_t*)&xb[(size_t)d * D + c0];  // self (premult by did)
        acc.x = b2f_lo(rs);
        acc.y = b2f_hi(rs);
    }

    for (int j = 0; j < c; j += 8) {
        int si[8];
        uint_t rv[8];
#pragma unroll
        for (int u = 0; u < 8; ++u) {
            int idx = j + u;
            si[u] = srcid[base + (idx < c ? idx : c - 1)];
        }
#pragma unroll
        for (int u = 0; u < 8; ++u) {
            rv[u] = *(const uint_t*)&xb[(size_t)si[u] * D + c0];
        }
#pragma unroll
        for (int u = 0; u < 8; ++u) {
            if (j + u < c) {
                acc.x += b2f_lo(rv[u]);
                acc.y += b2f_hi(rv[u]);
            }
        }
    }

    float2 agg = {did * acc.x, did * acc.y};
    *(float2*)&Lagg[nl * 64 + c0] = agg;
    __syncthreads();

    // GEMM phase: wave handles rows wave*2, wave*2+1
    float ssum = 0.0f, sqsum = 0.0f;
#pragma unroll
    for (int rr = 0; rr < 2; ++rr) {
        int r = wave * 2 + rr;
        int dd = blockIdx.x * 8 + r;
        float xv = Lagg[r * 64 + lane];
        float o = 0.0f;
#pragma unroll
        for (int k = 0; k < 64; ++k) {
            o += __shfl(xv, k) * Ws[k * 64 + lane];
        }
        if (dd < n) {
            out[(size_t)dd * D + lane] = o;
            ssum += o;
            sqsum += o * o;
        }
    }
    ls[wave][lane] = ssum;
    lq[wave][lane] = sqsum;
    __syncthreads();
    if (tid < 64) {
        float ts = ls[0][tid] + ls[1][tid] + ls[2][tid] + ls[3][tid];
        float tq = lq[0][tid] + lq[1][tid] + lq[2][tid] + lq[3][tid];
        float* slot = sums16 + (size_t)(blockIdx.x & 15) * 128;
        atomicAdd(&slot[tid], ts);
        atomicAdd(&slot[64 + tid], tq);
    }
}

// fold 16 slots -> final sums (stored at sums16 + 2048)
__global__ void k_finalize(float* sums16) {
    int i = threadIdx.x;  // 128 threads
    float s = 0.0f;
#pragma unroll
    for (int j = 0; j < 16; ++j) s += sums16[j * 128 + i];
    sums16[2048 + i] = s;
}

// ================= BN apply + ReLU (float4, in place) =================
// GCN bias b cancels exactly in BatchNorm: omitted.
__global__ void k_bn_apply(float* out, const float* __restrict__ sums,
                           const float* __restrict__ bnw, const float* __restrict__ bnb,
                           int n) {
    int i = blockIdx.x * blockDim.x + threadIdx.x;
    int total = n * (D / 4);
    if (i >= total) return;
    int c0 = (i * 4) & 63;
    const float invn = 1.0f / (float)NN;
    float4 v = ((const float4*)out)[i];
    float r[4] = {v.x, v.y, v.z, v.w};
#pragma unroll
    for (int j = 0; j < 4; ++j) {
        int c = c0 + j;
        float mean = sums[c] * invn;
        float var = sums[64 + c] * invn - mean * mean;
        if (var < 0.0f) var = 0.0f;
        float scale = bnw[c] * rsqrtf(var + BN_EPS);
        float y = (r[j] - mean) * scale + bnb[c];
        r[j] = y > 0.0f ? y : 0.0f;
    }
    float4 o = {r[0], r[1], r[2], r[3]};
    ((float4*)out)[i] = o;
}

extern "C" void kernel_launch(void* const* d_in, const int* in_sizes, int n_in,
                              void* d_out, int out_size, void* d_ws, size_t ws_size,
                              hipStream_t stream) {
    const float* x = (const float*)d_in[0];
    const int* ei = (const int*)d_in[1];
    const float* W = (const float*)d_in[3];
    const float* bnw = (const float*)d_in[5];
    const float* bnb = (const float*)d_in[6];
    float* out = (float*)d_out;

    const int n = in_sizes[0] / D;   // 100000
    const int E = in_sizes[1] / 2;   // 1600000
    const int* src = ei;
    const int* dst = ei + E;

    int* cnt = (int*)d_ws;
    int* row_ptr = cnt + n;
    int* cursor = row_ptr + n;
    float* dinv = (float*)(cursor + n);
    int* srcid = (int*)(dinv + n);
    int* bsum = srcid + E;                  // 128 ints
    float* sums16 = (float*)(bsum + 128);   // 16*128 slots + 128 final
    float* sums = sums16 + 2048;
    size_t off = ((size_t)((char*)(sums16 + 2176) - (char*)d_ws) + 15) & ~(size_t)15;
    ushort_t* xb = (ushort_t*)((char*)d_ws + off);

    const int nb = (n + 1023) / 1024;  // 98

    k_zero<<<(n + 255) / 256, 256, 0, stream>>>(cnt, sums16, n);
    k_count8<<<((E + 7) / 8 + 255) / 256, 256, 0, stream>>>(src, dst, cnt, E);
    k_dinv_xb<<<(n * (D / 4) + 255) / 256, 256, 0, stream>>>(cnt, x, dinv, xb, n);
    k_scanA<<<nb, 1024, 0, stream>>>(cnt, row_ptr, bsum, n);
    k_scanB<<<1, 128, 0, stream>>>(bsum, nb);
    k_scanC<<<(n + 255) / 256, 256, 0, stream>>>(row_ptr, cursor, bsum, n);
    k_place8<<<((E + 7) / 8 + 255) / 256, 256, 0, stream>>>(src, dst, cursor, srcid, E);

    k_gather2<<<(n + 7) / 8, 256, 0, stream>>>(row_ptr, cnt, srcid, xb, dinv, W,
                                               out, sums16, n);
    k_finalize<<<1, 128, 0, stream>>>(sums16);
    k_bn_apply<<<(n * (D / 4) + 255) / 256, 256, 0, stream>>>(out, sums, bnw, bnb, n);
}